// Round 7
// baseline (635.573 us; speedup 1.0000x reference)
//
#include <hip/hip_runtime.h>

#define WDIM 160
#define CH 12
#define BLK 256

// binning params
#define CELL 8
#define NB 20                    // cells per dim
#define NBUCKETS (NB*NB*NB)      // 8000
#define NBPAD 8192               // padded (pow2) bucket count
#define NPART 128                // point partitions (= hist/scatter blocks)

typedef float v4f __attribute__((ext_vector_type(4)));
typedef unsigned u32;

__device__ __forceinline__ void fma4(v4f& a, float w, const v4f& v) {
    a.x = fmaf(w, v.x, a.x);
    a.y = fmaf(w, v.y, a.y);
    a.z = fmaf(w, v.z, a.z);
    a.w = fmaf(w, v.w, a.w);
}

__device__ __forceinline__ void point_prep(const float* xyz, int i,
                                           float& px, float& py, float& pz,
                                           int& x0, int& y0, int& z0, int& bucket) {
    px = fminf(fmaxf(xyz[3*i+0] * 159.0f, 0.0f), 159.0f);
    py = fminf(fmaxf(xyz[3*i+1] * 159.0f, 0.0f), 159.0f);
    pz = fminf(fmaxf(xyz[3*i+2] * 159.0f, 0.0f), 159.0f);
    x0 = (int)px; y0 = (int)py; z0 = (int)pz;            // px>=0: trunc == floor
    bucket = ((x0 >> 3) * NB + (y0 >> 3)) * NB + (z0 >> 3);
}

// ---- K1: per-part histogram, NO global atomics ----
__global__ __launch_bounds__(BLK) void hist_kernel(const float* __restrict__ xyz,
                                                   u32* __restrict__ hist_part, int n) {
    __shared__ u32 lh[NBPAD];
    for (int k = threadIdx.x; k < NBPAD; k += BLK) lh[k] = 0;
    __syncthreads();
    const int stride = NPART * BLK;
    for (int i = blockIdx.x * BLK + threadIdx.x; i < n; i += stride) {
        float px, py, pz; int x0, y0, z0, b;
        point_prep(xyz, i, px, py, pz, x0, y0, z0, b);
        atomicAdd(&lh[b], 1u);               // LDS atomic only
    }
    __syncthreads();
    u32* dst = hist_part + (size_t)blockIdx.x * NBPAD;
    for (int k = threadIdx.x; k < NBPAD; k += BLK) dst[k] = lh[k];
}

// ---- K2a: per-bucket totals across parts (coalesced) ----
__global__ __launch_bounds__(BLK) void btot_kernel(const u32* __restrict__ hist_part,
                                                   u32* __restrict__ tot) {
    const int b = blockIdx.x * BLK + threadIdx.x;     // 0..8191
    u32 s = 0;
    for (int p = 0; p < NPART; p++) s += hist_part[(size_t)p * NBPAD + b];
    tot[b] = s;
}

// ---- K2b: exclusive scan of 8192 totals (single block) ----
__global__ __launch_bounds__(BLK) void scan_kernel(const u32* __restrict__ tot,
                                                   u32* __restrict__ starts) {
    __shared__ u32 part[BLK];
    __shared__ u32 base[BLK];
    const int t = threadIdx.x;
    u32 h[32];
    u32 s = 0;
    for (int j = 0; j < 32; j++) { h[j] = tot[t*32 + j]; s += h[j]; }
    part[t] = s;
    __syncthreads();
    if (t == 0) {
        u32 run = 0;
        for (int k = 0; k < BLK; k++) { base[k] = run; run += part[k]; }
        starts[NBPAD] = run;   // == n (pad buckets are empty)
    }
    __syncthreads();
    u32 run = base[t];
    for (int j = 0; j < 32; j++) {
        starts[t*32 + j] = run;
        run += h[j];
    }
}

// ---- K2c: per-(part,bucket) start offsets (coalesced both sides) ----
__global__ __launch_bounds__(BLK) void pscan_kernel(const u32* __restrict__ hist_part,
                                                    const u32* __restrict__ starts,
                                                    u32* __restrict__ starts_part) {
    const int b = blockIdx.x * BLK + threadIdx.x;     // 0..8191
    u32 run = starts[b];
    for (int p = 0; p < NPART; p++) {
        starts_part[(size_t)p * NBPAD + b] = run;
        run += hist_part[(size_t)p * NBPAD + b];
    }
}

// ---- K3: scatter records into bucket order, LDS cursors, NO global atomics ----
// block p MUST cover the same point set as hist block p (identical loop).
__global__ __launch_bounds__(BLK) void scatter_kernel(const float* __restrict__ xyz,
                                                      const u32* __restrict__ starts_part,
                                                      v4f* __restrict__ recs,
                                                      u32* __restrict__ inv, int n) {
    __shared__ u32 cur[NBPAD];
    const u32* sp = starts_part + (size_t)blockIdx.x * NBPAD;
    for (int k = threadIdx.x; k < NBPAD; k += BLK) cur[k] = sp[k];
    __syncthreads();
    const int stride = NPART * BLK;
    for (int i = blockIdx.x * BLK + threadIdx.x; i < n; i += stride) {
        float px, py, pz; int x0, y0, z0, b;
        point_prep(xyz, i, px, py, pz, x0, y0, z0, b);
        u32 pos = atomicAdd(&cur[b], 1u);             // LDS atomic only
        v4f r; r.x = px; r.y = py; r.z = pz; r.w = __uint_as_float((u32)i);
        recs[pos] = r;
        inv[i] = pos;                                  // coalesced
    }
}

// ---- K4: per-bucket gather, DIRECT L2 reads (single change vs round-3) ----
// Points are bucket-sorted -> each block's grid reads live in a hot ~35 KB
// L2 window; XCD swizzle keeps neighboring buckets on one XCD's L2.
// DIRECT=1: scattered NT stores to out (fallback tier).
// DIRECT=0: sequential plain stores to resbuf in bucket order.
template<int DIRECT>
__global__ __launch_bounds__(BLK) void gather_kernel(const v4f* __restrict__ recs,
                                                     const u32* __restrict__ starts,
                                                     const float* __restrict__ grid,
                                                     v4f* __restrict__ resbuf,
                                                     float* __restrict__ out) {
    const unsigned bb = blockIdx.x;
    const unsigned bucket = (bb & 7u) * (NBUCKETS / 8u) + (bb >> 3);

    const u32 s = starts[bucket], e = starts[bucket + 1];
    for (u32 p = s + threadIdx.x; p < e; p += BLK) {
        v4f r = recs[p];
        const float px = r.x, py = r.y, pz = r.z;

        const int x0 = (int)px, y0 = (int)py, z0 = (int)pz;
        const float fx = px - (float)x0, fy = py - (float)y0, fz = pz - (float)z0;
        const float gx = 1.0f - fx, gy = 1.0f - fy, gz = 1.0f - fz;
        const int x1 = min(x0 + 1, WDIM - 1), y1 = min(y0 + 1, WDIM - 1), z1 = min(z0 + 1, WDIM - 1);

        const float w000 = gx*gy*gz, w001 = gx*gy*fz, w010 = gx*fy*gz, w011 = gx*fy*fz;
        const float w100 = fx*gy*gz, w101 = fx*gy*fz, w110 = fx*fy*gz, w111 = fx*fy*fz;

        const int b00 = ((x0*WDIM + y0)*WDIM)*CH, b01 = ((x0*WDIM + y1)*WDIM)*CH;
        const int b10 = ((x1*WDIM + y0)*WDIM)*CH, b11 = ((x1*WDIM + y1)*WDIM)*CH;
        const int oz0 = z0*CH, oz1 = z1*CH;

        v4f a0 = (v4f)(0.0f), a1 = (v4f)(0.0f), a2 = (v4f)(0.0f);
        const v4f* c;
        c = reinterpret_cast<const v4f*>(grid + b00 + oz0); fma4(a0,w000,c[0]); fma4(a1,w000,c[1]); fma4(a2,w000,c[2]);
        c = reinterpret_cast<const v4f*>(grid + b00 + oz1); fma4(a0,w001,c[0]); fma4(a1,w001,c[1]); fma4(a2,w001,c[2]);
        c = reinterpret_cast<const v4f*>(grid + b01 + oz0); fma4(a0,w010,c[0]); fma4(a1,w010,c[1]); fma4(a2,w010,c[2]);
        c = reinterpret_cast<const v4f*>(grid + b01 + oz1); fma4(a0,w011,c[0]); fma4(a1,w011,c[1]); fma4(a2,w011,c[2]);
        c = reinterpret_cast<const v4f*>(grid + b10 + oz0); fma4(a0,w100,c[0]); fma4(a1,w100,c[1]); fma4(a2,w100,c[2]);
        c = reinterpret_cast<const v4f*>(grid + b10 + oz1); fma4(a0,w101,c[0]); fma4(a1,w101,c[1]); fma4(a2,w101,c[2]);
        c = reinterpret_cast<const v4f*>(grid + b11 + oz0); fma4(a0,w110,c[0]); fma4(a1,w110,c[1]); fma4(a2,w110,c[2]);
        c = reinterpret_cast<const v4f*>(grid + b11 + oz1); fma4(a0,w111,c[0]); fma4(a1,w111,c[1]); fma4(a2,w111,c[2]);

        if (DIRECT) {
            const u32 idx = __float_as_uint(r.w);
            v4f* o = reinterpret_cast<v4f*>(out + (size_t)idx * CH);
            __builtin_nontemporal_store(a0, o + 0);
            __builtin_nontemporal_store(a1, o + 1);
            __builtin_nontemporal_store(a2, o + 2);
        } else {
            v4f* o = resbuf + (size_t)p * 3;   // sequential in bucket order
            o[0] = a0; o[1] = a1; o[2] = a2;   // plain stores -> full-line merge
        }
    }
}

// ---- K5: inverse permute, sequential full-line out writes ----
__global__ __launch_bounds__(BLK) void permute_kernel(const v4f* __restrict__ resbuf,
                                                      const u32* __restrict__ inv,
                                                      float* __restrict__ out, int n) {
    const int stride = gridDim.x * BLK;
    for (int i = blockIdx.x * BLK + threadIdx.x; i < n; i += stride) {
        const u32 pos = inv[i];
        const v4f* sp = resbuf + (size_t)pos * 3;   // random read, L2/L3-resident
        v4f a0 = sp[0], a1 = sp[1], a2 = sp[2];
        v4f* o = reinterpret_cast<v4f*>(out + (size_t)i * CH);
        __builtin_nontemporal_store(a0, o + 0);
        __builtin_nontemporal_store(a1, o + 1);
        __builtin_nontemporal_store(a2, o + 2);
    }
}

// ---- fallback: direct kernel if ws too small ----
__global__ __launch_bounds__(BLK) void trilerp_direct(const float* __restrict__ xyz,
                                                      const float* __restrict__ grid,
                                                      float* __restrict__ out, int n) {
    const int i = blockIdx.x * BLK + threadIdx.x;
    if (i >= n) return;
    float px, py, pz; int x0, y0, z0, b;
    point_prep(xyz, i, px, py, pz, x0, y0, z0, b);
    const float fx = px - (float)x0, fy = py - (float)y0, fz = pz - (float)z0;
    const float gx = 1.0f - fx, gy = 1.0f - fy, gz = 1.0f - fz;
    const int x1 = min(x0 + 1, WDIM - 1), y1 = min(y0 + 1, WDIM - 1), z1 = min(z0 + 1, WDIM - 1);
    const float w000 = gx*gy*gz, w001 = gx*gy*fz, w010 = gx*fy*gz, w011 = gx*fy*fz;
    const float w100 = fx*gy*gz, w101 = fx*gy*fz, w110 = fx*fy*gz, w111 = fx*fy*fz;
    const int b00 = ((x0*WDIM + y0)*WDIM)*CH, b01 = ((x0*WDIM + y1)*WDIM)*CH;
    const int b10 = ((x1*WDIM + y0)*WDIM)*CH, b11 = ((x1*WDIM + y1)*WDIM)*CH;
    const int oz0 = z0*CH, oz1 = z1*CH;
    v4f a0 = (v4f)(0.0f), a1 = (v4f)(0.0f), a2 = (v4f)(0.0f);
    const v4f* c;
    c = reinterpret_cast<const v4f*>(grid + b00 + oz0); fma4(a0,w000,c[0]); fma4(a1,w000,c[1]); fma4(a2,w000,c[2]);
    c = reinterpret_cast<const v4f*>(grid + b00 + oz1); fma4(a0,w001,c[0]); fma4(a1,w001,c[1]); fma4(a2,w001,c[2]);
    c = reinterpret_cast<const v4f*>(grid + b01 + oz0); fma4(a0,w010,c[0]); fma4(a1,w010,c[1]); fma4(a2,w010,c[2]);
    c = reinterpret_cast<const v4f*>(grid + b01 + oz1); fma4(a0,w011,c[0]); fma4(a1,w011,c[1]); fma4(a2,w011,c[2]);
    c = reinterpret_cast<const v4f*>(grid + b10 + oz0); fma4(a0,w100,c[0]); fma4(a1,w100,c[1]); fma4(a2,w100,c[2]);
    c = reinterpret_cast<const v4f*>(grid + b10 + oz1); fma4(a0,w101,c[0]); fma4(a1,w101,c[1]); fma4(a2,w101,c[2]);
    c = reinterpret_cast<const v4f*>(grid + b11 + oz0); fma4(a0,w110,c[0]); fma4(a1,w110,c[1]); fma4(a2,w110,c[2]);
    c = reinterpret_cast<const v4f*>(grid + b11 + oz1); fma4(a0,w111,c[0]); fma4(a1,w111,c[1]); fma4(a2,w111,c[2]);
    v4f* o = reinterpret_cast<v4f*>(out + (size_t)i * CH);
    __builtin_nontemporal_store(a0, o + 0);
    __builtin_nontemporal_store(a1, o + 1);
    __builtin_nontemporal_store(a2, o + 2);
}

extern "C" void kernel_launch(void* const* d_in, const int* in_sizes, int n_in,
                              void* d_out, int out_size, void* d_ws, size_t ws_size,
                              hipStream_t stream) {
    const float* xyz  = (const float*)d_in[0];
    const float* grid = (const float*)d_in[1];
    float* out = (float*)d_out;
    const int n = in_sizes[0] / 3;   // 2,000,000 points
    if (n <= 0) return;

    // workspace layout, each sub-buffer 256-B aligned
    const size_t A = 256;
    const size_t recs_bytes    = ((size_t)n * 16        + A-1) & ~(A-1);
    const size_t resbuf_bytes  = ((size_t)n * 48        + A-1) & ~(A-1);
    const size_t inv_bytes     = ((size_t)n * 4         + A-1) & ~(A-1);
    const size_t hpart_bytes   = ((size_t)NPART*NBPAD*4 + A-1) & ~(A-1);
    const size_t tot_bytes     = ((size_t)NBPAD * 4     + A-1) & ~(A-1);
    const size_t starts_bytes  = ((size_t)(NBPAD+2) * 4 + A-1) & ~(A-1);
    const size_t spart_bytes   = ((size_t)NPART*NBPAD*4 + A-1) & ~(A-1);

    const size_t fixed_bytes = recs_bytes + inv_bytes + hpart_bytes +
                               tot_bytes + starts_bytes + spart_bytes;
    const size_t full_needed = fixed_bytes + resbuf_bytes;
    const size_t mid_needed  = fixed_bytes;

    if (ws_size < mid_needed) {
        trilerp_direct<<<(n + BLK - 1) / BLK, BLK, 0, stream>>>(xyz, grid, out, n);
        return;
    }
    const bool full = (ws_size >= full_needed);

    char* ws = (char*)d_ws;
    size_t off = 0;
    v4f* recs        = (v4f*)(ws + off);  off += recs_bytes;
    v4f* resbuf      = nullptr;
    if (full) { resbuf = (v4f*)(ws + off); off += resbuf_bytes; }
    u32* inv         = (u32*)(ws + off);  off += inv_bytes;
    u32* hist_part   = (u32*)(ws + off);  off += hpart_bytes;
    u32* tot         = (u32*)(ws + off);  off += tot_bytes;
    u32* starts      = (u32*)(ws + off);  off += starts_bytes;
    u32* starts_part = (u32*)(ws + off);  off += spart_bytes;

    hist_kernel   <<<NPART,      BLK, 0, stream>>>(xyz, hist_part, n);
    btot_kernel   <<<NBPAD/BLK,  BLK, 0, stream>>>(hist_part, tot);
    scan_kernel   <<<1,          BLK, 0, stream>>>(tot, starts);
    pscan_kernel  <<<NBPAD/BLK,  BLK, 0, stream>>>(hist_part, starts, starts_part);
    scatter_kernel<<<NPART,      BLK, 0, stream>>>(xyz, starts_part, recs, inv, n);
    if (full) {
        gather_kernel<0><<<NBUCKETS, BLK, 0, stream>>>(recs, starts, grid, resbuf, out);
        permute_kernel  <<<2048,     BLK, 0, stream>>>(resbuf, inv, out, n);
    } else {
        gather_kernel<1><<<NBUCKETS, BLK, 0, stream>>>(recs, starts, grid, resbuf, out);
    }
}

// Round 8
// 491.213 us; speedup vs baseline: 1.2939x; 1.2939x over previous
//
#include <hip/hip_runtime.h>

#define WDIM 160
#define CH 12
#define BLK 256

// binning params
#define CELL 8
#define NB 20                    // cells per dim
#define NBUCKETS (NB*NB*NB)      // 8000
#define NBPAD 8192               // padded (pow2) bucket count
#define NPART 128                // point partitions (= hist/scatter blocks)
#define SUB 9                    // subgrid voxels per dim (cell + 1 halo)
#define SUBV (SUB*SUB*SUB)       // 729 voxels
#define SUBQ (SUBV*3)            // 2187 float4s = 34992 B LDS
#define SUBQ_PAD 2304            // 9 * BLK, guard-free stage loop

typedef float v4f __attribute__((ext_vector_type(4)));
typedef unsigned u32;

#define AS1 __attribute__((address_space(1)))
#define AS3 __attribute__((address_space(3)))

__device__ __forceinline__ void fma4(v4f& a, float w, const v4f& v) {
    a.x = fmaf(w, v.x, a.x);
    a.y = fmaf(w, v.y, a.y);
    a.z = fmaf(w, v.z, a.z);
    a.w = fmaf(w, v.w, a.w);
}

__device__ __forceinline__ void prep_xyz(float X, float Y, float Z,
                                         float& px, float& py, float& pz,
                                         int& x0, int& y0, int& z0, int& bucket) {
    px = fminf(fmaxf(X * 159.0f, 0.0f), 159.0f);
    py = fminf(fmaxf(Y * 159.0f, 0.0f), 159.0f);
    pz = fminf(fmaxf(Z * 159.0f, 0.0f), 159.0f);
    x0 = (int)px; y0 = (int)py; z0 = (int)pz;            // px>=0: trunc == floor
    bucket = ((x0 >> 3) * NB + (y0 >> 3)) * NB + (z0 >> 3);
}

__device__ __forceinline__ void point_prep(const float* xyz, int i,
                                           float& px, float& py, float& pz,
                                           int& x0, int& y0, int& z0, int& bucket) {
    prep_xyz(xyz[3*i+0], xyz[3*i+1], xyz[3*i+2], px, py, pz, x0, y0, z0, bucket);
}

// ---- K1: per-part histogram, NO global atomics, 4 pts/thread vectorized ----
__global__ __launch_bounds__(BLK) void hist_kernel(const float* __restrict__ xyz,
                                                   u32* __restrict__ hist_part, int n) {
    __shared__ u32 lh[NBPAD];
    for (int k = threadIdx.x; k < NBPAD; k += BLK) lh[k] = 0;
    __syncthreads();
    const int ng4 = n >> 2;
    const int stride = NPART * BLK;
    for (int g = blockIdx.x * BLK + threadIdx.x; g < ng4; g += stride) {
        const v4f* xb = reinterpret_cast<const v4f*>(xyz + 12 * (size_t)g);
        v4f A = xb[0], B = xb[1], C = xb[2];
        float px, py, pz; int x0, y0, z0, b;
        prep_xyz(A.x, A.y, A.z, px, py, pz, x0, y0, z0, b); atomicAdd(&lh[b], 1u);
        prep_xyz(A.w, B.x, B.y, px, py, pz, x0, y0, z0, b); atomicAdd(&lh[b], 1u);
        prep_xyz(B.z, B.w, C.x, px, py, pz, x0, y0, z0, b); atomicAdd(&lh[b], 1u);
        prep_xyz(C.y, C.z, C.w, px, py, pz, x0, y0, z0, b); atomicAdd(&lh[b], 1u);
    }
    // tail (n % 4) — identical scheme in scatter tail
    for (int i = (ng4 << 2) + blockIdx.x * BLK + threadIdx.x; i < n; i += stride) {
        float px, py, pz; int x0, y0, z0, b;
        point_prep(xyz, i, px, py, pz, x0, y0, z0, b);
        atomicAdd(&lh[b], 1u);
    }
    __syncthreads();
    u32* dst = hist_part + (size_t)blockIdx.x * NBPAD;
    for (int k = threadIdx.x; k < NBPAD; k += BLK) dst[k] = lh[k];
}

// ---- K2a: per-bucket totals across parts (coalesced) ----
__global__ __launch_bounds__(BLK) void btot_kernel(const u32* __restrict__ hist_part,
                                                   u32* __restrict__ tot) {
    const int b = blockIdx.x * BLK + threadIdx.x;     // 0..8191
    u32 s = 0;
    for (int p = 0; p < NPART; p++) s += hist_part[(size_t)p * NBPAD + b];
    tot[b] = s;
}

// ---- K2b: exclusive scan of 8192 totals (single block) ----
__global__ __launch_bounds__(BLK) void scan_kernel(const u32* __restrict__ tot,
                                                   u32* __restrict__ starts) {
    __shared__ u32 part[BLK];
    __shared__ u32 base[BLK];
    const int t = threadIdx.x;
    u32 h[32];
    u32 s = 0;
    for (int j = 0; j < 32; j++) { h[j] = tot[t*32 + j]; s += h[j]; }
    part[t] = s;
    __syncthreads();
    if (t == 0) {
        u32 run = 0;
        for (int k = 0; k < BLK; k++) { base[k] = run; run += part[k]; }
        starts[NBPAD] = run;   // == n (pad buckets are empty)
    }
    __syncthreads();
    u32 run = base[t];
    for (int j = 0; j < 32; j++) {
        starts[t*32 + j] = run;
        run += h[j];
    }
}

// ---- K2c: per-(part,bucket) start offsets (coalesced both sides) ----
__global__ __launch_bounds__(BLK) void pscan_kernel(const u32* __restrict__ hist_part,
                                                    const u32* __restrict__ starts,
                                                    u32* __restrict__ starts_part) {
    const int b = blockIdx.x * BLK + threadIdx.x;     // 0..8191
    u32 run = starts[b];
    for (int p = 0; p < NPART; p++) {
        starts_part[(size_t)p * NBPAD + b] = run;
        run += hist_part[(size_t)p * NBPAD + b];
    }
}

// ---- K3: scatter records into bucket order, LDS cursors, NO global atomics ----
// block p MUST cover the same point set as hist block p (identical loops).
__global__ __launch_bounds__(BLK) void scatter_kernel(const float* __restrict__ xyz,
                                                      const u32* __restrict__ starts_part,
                                                      v4f* __restrict__ recs,
                                                      u32* __restrict__ inv, int n) {
    __shared__ u32 cur[NBPAD];
    const u32* sp = starts_part + (size_t)blockIdx.x * NBPAD;
    for (int k = threadIdx.x; k < NBPAD; k += BLK) cur[k] = sp[k];
    __syncthreads();
    const int ng4 = n >> 2;
    const int stride = NPART * BLK;
    for (int g = blockIdx.x * BLK + threadIdx.x; g < ng4; g += stride) {
        const v4f* xb = reinterpret_cast<const v4f*>(xyz + 12 * (size_t)g);
        v4f A = xb[0], B = xb[1], C = xb[2];
        const int i0 = g << 2;
        float px, py, pz; int x0, y0, z0, b;
        prep_xyz(A.x, A.y, A.z, px, py, pz, x0, y0, z0, b);
        { u32 pos = atomicAdd(&cur[b], 1u);
          v4f r; r.x = px; r.y = py; r.z = pz; r.w = __uint_as_float((u32)(i0+0));
          recs[pos] = r; inv[i0+0] = pos; }
        prep_xyz(A.w, B.x, B.y, px, py, pz, x0, y0, z0, b);
        { u32 pos = atomicAdd(&cur[b], 1u);
          v4f r; r.x = px; r.y = py; r.z = pz; r.w = __uint_as_float((u32)(i0+1));
          recs[pos] = r; inv[i0+1] = pos; }
        prep_xyz(B.z, B.w, C.x, px, py, pz, x0, y0, z0, b);
        { u32 pos = atomicAdd(&cur[b], 1u);
          v4f r; r.x = px; r.y = py; r.z = pz; r.w = __uint_as_float((u32)(i0+2));
          recs[pos] = r; inv[i0+2] = pos; }
        prep_xyz(C.y, C.z, C.w, px, py, pz, x0, y0, z0, b);
        { u32 pos = atomicAdd(&cur[b], 1u);
          v4f r; r.x = px; r.y = py; r.z = pz; r.w = __uint_as_float((u32)(i0+3));
          recs[pos] = r; inv[i0+3] = pos; }
    }
    for (int i = (ng4 << 2) + blockIdx.x * BLK + threadIdx.x; i < n; i += stride) {
        float px, py, pz; int x0, y0, z0, b;
        point_prep(xyz, i, px, py, pz, x0, y0, z0, b);
        u32 pos = atomicAdd(&cur[b], 1u);
        v4f r; r.x = px; r.y = py; r.z = pz; r.w = __uint_as_float((u32)i);
        recs[pos] = r;
        inv[i] = pos;
    }
}

// ---- K4: per-bucket gather with async LDS-staged subgrid (round-3 form) ----
// DIRECT=1: scattered NT stores to out (fallback tier).
// DIRECT=0: sequential plain stores to resbuf in bucket order (full-line).
template<int DIRECT>
__global__ __launch_bounds__(BLK, 4) void gather_kernel(const v4f* __restrict__ recs,
                                                        const u32* __restrict__ starts,
                                                        const float* __restrict__ grid,
                                                        v4f* __restrict__ resbuf,
                                                        float* __restrict__ out) {
    __shared__ v4f sg[SUBQ_PAD];

    // XCD-locality swizzle
    const unsigned bb = blockIdx.x;
    const unsigned bucket = (bb & 7u) * (NBUCKETS / 8u) + (bb >> 3);
    const int bx = (int)(bucket / (NB*NB));
    const int rem = (int)bucket - bx * (NB*NB);
    const int by = rem / NB, bz = rem - (rem / NB) * NB;
    const int gx0 = bx * CELL, gy0 = by * CELL, gz0 = bz * CELL;

    const int t = threadIdx.x;
#pragma unroll
    for (int k = 0; k < SUBQ_PAD / BLK; ++k) {
        int f  = t + k * BLK;
        int fc = min(f, SUBQ - 1);            // pad lanes re-load last quad
        int v  = fc / 3, c = fc - v * 3;
        int lx = v / (SUB*SUB); int r = v - lx * (SUB*SUB);
        int ly = r / SUB;       int lz = r - ly * SUB;
        int gx = min(gx0 + lx, WDIM - 1);
        int gy = min(gy0 + ly, WDIM - 1);
        int gz = min(gz0 + lz, WDIM - 1);
        const float* src = grid + (size_t)(((gx * WDIM + gy) * WDIM + gz) * CH) + c * 4;
        __builtin_amdgcn_global_load_lds((const AS1 unsigned*)src,
                                         (AS3 unsigned*)&sg[f], 16, 0, 0);
    }
    __syncthreads();   // drains vmcnt -> LDS valid

    const u32 s = starts[bucket], e = starts[bucket + 1];
    for (u32 p = s + threadIdx.x; p < e; p += BLK) {
        v4f r = recs[p];
        const float px = r.x, py = r.y, pz = r.z;

        const int x0 = (int)px, y0 = (int)py, z0 = (int)pz;
        const float fx = px - (float)x0, fy = py - (float)y0, fz = pz - (float)z0;
        const float gx = 1.0f - fx, gy = 1.0f - fy, gz = 1.0f - fz;
        const int lx0 = x0 - gx0, ly0 = y0 - gy0, lz0 = z0 - gz0;

        const float w000 = gx * gy * gz, w001 = gx * gy * fz;
        const float w010 = gx * fy * gz, w011 = gx * fy * fz;
        const float w100 = fx * gy * gz, w101 = fx * gy * fz;
        const float w110 = fx * fy * gz, w111 = fx * fy * fz;

        const int q000 = (lx0 * (SUB*SUB) + ly0 * SUB + lz0) * 3;
        const int q001 = q000 + 3;
        const int q010 = q000 + SUB * 3;
        const int q011 = q010 + 3;
        const int q100 = q000 + (SUB*SUB) * 3;
        const int q101 = q100 + 3;
        const int q110 = q100 + SUB * 3;
        const int q111 = q110 + 3;

        v4f a0 = (v4f)(0.0f), a1 = (v4f)(0.0f), a2 = (v4f)(0.0f);
        fma4(a0, w000, sg[q000+0]); fma4(a1, w000, sg[q000+1]); fma4(a2, w000, sg[q000+2]);
        fma4(a0, w001, sg[q001+0]); fma4(a1, w001, sg[q001+1]); fma4(a2, w001, sg[q001+2]);
        fma4(a0, w010, sg[q010+0]); fma4(a1, w010, sg[q010+1]); fma4(a2, w010, sg[q010+2]);
        fma4(a0, w011, sg[q011+0]); fma4(a1, w011, sg[q011+1]); fma4(a2, w011, sg[q011+2]);
        fma4(a0, w100, sg[q100+0]); fma4(a1, w100, sg[q100+1]); fma4(a2, w100, sg[q100+2]);
        fma4(a0, w101, sg[q101+0]); fma4(a1, w101, sg[q101+1]); fma4(a2, w101, sg[q101+2]);
        fma4(a0, w110, sg[q110+0]); fma4(a1, w110, sg[q110+1]); fma4(a2, w110, sg[q110+2]);
        fma4(a0, w111, sg[q111+0]); fma4(a1, w111, sg[q111+1]); fma4(a2, w111, sg[q111+2]);

        if (DIRECT) {
            const u32 idx = __float_as_uint(r.w);
            v4f* o = reinterpret_cast<v4f*>(out + (size_t)idx * CH);
            __builtin_nontemporal_store(a0, o + 0);
            __builtin_nontemporal_store(a1, o + 1);
            __builtin_nontemporal_store(a2, o + 2);
        } else {
            v4f* o = resbuf + (size_t)p * 3;   // sequential in bucket order
            o[0] = a0; o[1] = a1; o[2] = a2;   // plain stores -> full-line merge
        }
    }
}

// ---- K5: inverse permute, sequential full-line out writes ----
__global__ __launch_bounds__(BLK) void permute_kernel(const v4f* __restrict__ resbuf,
                                                      const u32* __restrict__ inv,
                                                      float* __restrict__ out, int n) {
    const int stride = gridDim.x * BLK;
    for (int i = blockIdx.x * BLK + threadIdx.x; i < n; i += stride) {
        const u32 pos = inv[i];
        const v4f* sp = resbuf + (size_t)pos * 3;   // random read, L2/L3-resident
        v4f a0 = sp[0], a1 = sp[1], a2 = sp[2];
        v4f* o = reinterpret_cast<v4f*>(out + (size_t)i * CH);
        __builtin_nontemporal_store(a0, o + 0);
        __builtin_nontemporal_store(a1, o + 1);
        __builtin_nontemporal_store(a2, o + 2);
    }
}

// ---- fallback: direct kernel if ws too small ----
__global__ __launch_bounds__(BLK) void trilerp_direct(const float* __restrict__ xyz,
                                                      const float* __restrict__ grid,
                                                      float* __restrict__ out, int n) {
    const int i = blockIdx.x * BLK + threadIdx.x;
    if (i >= n) return;
    float px, py, pz; int x0, y0, z0, b;
    point_prep(xyz, i, px, py, pz, x0, y0, z0, b);
    const float fx = px - (float)x0, fy = py - (float)y0, fz = pz - (float)z0;
    const float gx = 1.0f - fx, gy = 1.0f - fy, gz = 1.0f - fz;
    const int x1 = min(x0 + 1, WDIM - 1), y1 = min(y0 + 1, WDIM - 1), z1 = min(z0 + 1, WDIM - 1);
    const float w000 = gx*gy*gz, w001 = gx*gy*fz, w010 = gx*fy*gz, w011 = gx*fy*fz;
    const float w100 = fx*gy*gz, w101 = fx*gy*fz, w110 = fx*fy*gz, w111 = fx*fy*fz;
    const int b00 = ((x0*WDIM + y0)*WDIM)*CH, b01 = ((x0*WDIM + y1)*WDIM)*CH;
    const int b10 = ((x1*WDIM + y0)*WDIM)*CH, b11 = ((x1*WDIM + y1)*WDIM)*CH;
    const int oz0 = z0*CH, oz1 = z1*CH;
    v4f a0 = (v4f)(0.0f), a1 = (v4f)(0.0f), a2 = (v4f)(0.0f);
    const v4f* c;
    c = reinterpret_cast<const v4f*>(grid + b00 + oz0); fma4(a0,w000,c[0]); fma4(a1,w000,c[1]); fma4(a2,w000,c[2]);
    c = reinterpret_cast<const v4f*>(grid + b00 + oz1); fma4(a0,w001,c[0]); fma4(a1,w001,c[1]); fma4(a2,w001,c[2]);
    c = reinterpret_cast<const v4f*>(grid + b01 + oz0); fma4(a0,w010,c[0]); fma4(a1,w010,c[1]); fma4(a2,w010,c[2]);
    c = reinterpret_cast<const v4f*>(grid + b01 + oz1); fma4(a0,w011,c[0]); fma4(a1,w011,c[1]); fma4(a2,w011,c[2]);
    c = reinterpret_cast<const v4f*>(grid + b10 + oz0); fma4(a0,w100,c[0]); fma4(a1,w100,c[1]); fma4(a2,w100,c[2]);
    c = reinterpret_cast<const v4f*>(grid + b10 + oz1); fma4(a0,w101,c[0]); fma4(a1,w101,c[1]); fma4(a2,w101,c[2]);
    c = reinterpret_cast<const v4f*>(grid + b11 + oz0); fma4(a0,w110,c[0]); fma4(a1,w110,c[1]); fma4(a2,w110,c[2]);
    c = reinterpret_cast<const v4f*>(grid + b11 + oz1); fma4(a0,w111,c[0]); fma4(a1,w111,c[1]); fma4(a2,w111,c[2]);
    v4f* o = reinterpret_cast<v4f*>(out + (size_t)i * CH);
    __builtin_nontemporal_store(a0, o + 0);
    __builtin_nontemporal_store(a1, o + 1);
    __builtin_nontemporal_store(a2, o + 2);
}

extern "C" void kernel_launch(void* const* d_in, const int* in_sizes, int n_in,
                              void* d_out, int out_size, void* d_ws, size_t ws_size,
                              hipStream_t stream) {
    const float* xyz  = (const float*)d_in[0];
    const float* grid = (const float*)d_in[1];
    float* out = (float*)d_out;
    const int n = in_sizes[0] / 3;   // 2,000,000 points
    if (n <= 0) return;

    // workspace layout, each sub-buffer 256-B aligned
    const size_t A = 256;
    const size_t recs_bytes    = ((size_t)n * 16        + A-1) & ~(A-1);
    const size_t resbuf_bytes  = ((size_t)n * 48        + A-1) & ~(A-1);
    const size_t inv_bytes     = ((size_t)n * 4         + A-1) & ~(A-1);
    const size_t hpart_bytes   = ((size_t)NPART*NBPAD*4 + A-1) & ~(A-1);
    const size_t tot_bytes     = ((size_t)NBPAD * 4     + A-1) & ~(A-1);
    const size_t starts_bytes  = ((size_t)(NBPAD+2) * 4 + A-1) & ~(A-1);
    const size_t spart_bytes   = ((size_t)NPART*NBPAD*4 + A-1) & ~(A-1);

    const size_t fixed_bytes = recs_bytes + inv_bytes + hpart_bytes +
                               tot_bytes + starts_bytes + spart_bytes;
    const size_t full_needed = fixed_bytes + resbuf_bytes;
    const size_t mid_needed  = fixed_bytes;

    if (ws_size < mid_needed) {
        trilerp_direct<<<(n + BLK - 1) / BLK, BLK, 0, stream>>>(xyz, grid, out, n);
        return;
    }
    const bool full = (ws_size >= full_needed);

    char* ws = (char*)d_ws;
    size_t off = 0;
    v4f* recs        = (v4f*)(ws + off);  off += recs_bytes;
    v4f* resbuf      = nullptr;
    if (full) { resbuf = (v4f*)(ws + off); off += resbuf_bytes; }
    u32* inv         = (u32*)(ws + off);  off += inv_bytes;
    u32* hist_part   = (u32*)(ws + off);  off += hpart_bytes;
    u32* tot         = (u32*)(ws + off);  off += tot_bytes;
    u32* starts      = (u32*)(ws + off);  off += starts_bytes;
    u32* starts_part = (u32*)(ws + off);  off += spart_bytes;

    hist_kernel   <<<NPART,      BLK, 0, stream>>>(xyz, hist_part, n);
    btot_kernel   <<<NBPAD/BLK,  BLK, 0, stream>>>(hist_part, tot);
    scan_kernel   <<<1,          BLK, 0, stream>>>(tot, starts);
    pscan_kernel  <<<NBPAD/BLK,  BLK, 0, stream>>>(hist_part, starts, starts_part);
    scatter_kernel<<<NPART,      BLK, 0, stream>>>(xyz, starts_part, recs, inv, n);
    if (full) {
        gather_kernel<0><<<NBUCKETS, BLK, 0, stream>>>(recs, starts, grid, resbuf, out);
        permute_kernel  <<<2048,     BLK, 0, stream>>>(resbuf, inv, out, n);
    } else {
        gather_kernel<1><<<NBUCKETS, BLK, 0, stream>>>(recs, starts, grid, resbuf, out);
    }
}